// Round 6
// baseline (637.366 us; speedup 1.0000x reference)
//
#include <hip/hip_runtime.h>
#include <hip/hip_cooperative_groups.h>
#include <cmath>

namespace cg = cooperative_groups;

// GCN 2-layer, dims 1 -> 16 -> 2, N=100K, E=6.4M.
//
// Model (R1..R18, counter-validated):
//  - Each of the 4 edge passes (scatter, deg, aggf, agg2u64) sits at the
//    DS-pipe serial-RMW floor: 6.4M lane-atomics x 4.2cyc / 256CU = 43.5us.
//    Confirmed by R18: pair-cell ILP made aggf SLOWER (50.5us) while
//    VALUBusy 6%, HBM 8%, bank-conf 0, occ 59% -> not latency/BW/conflict.
//  - Ledger: 4x43.5 floor + ~11us node kernels + ~43us launch gaps = 228us.
//  - R14/R15 gathers, R16 global atomics: regressed (see history).
//  - R17 fusion regressed 3x/phase BUT was confounded: launch_bounds(512,4)
//    forced VGPR=32 (can't hold the 4-wide gather live set -> serialize).
// R19: fusion retry with the squeeze removed: __launch_bounds__(512) only,
// R13-identical phase bodies, grid=512 (2 blocks/CU), 6 grid.syncs replace
// 6 launch gaps. VGPR_Count is the disambiguator (expect 48-96). Fallback:
// exact R13 sequence.

static constexpr int CSH   = 11;           // log2 bucket width
static constexpr int CW    = 1 << CSH;     // 2048 nodes / bucket
static constexpr int MAXNC = 64;           // n <= 131072
static constexpr int NB1   = 512;          // scatter blocks / segments / grid

__host__ __device__ __forceinline__ int chunk_of(int e) {
    return ((e + NB1 * 4 - 1) / (NB1 * 4)) * 4;   // 4-aligned per-block chunk
}

__device__ __forceinline__ unsigned long long pack_u(float2 uv) {
    float cx = fminf(fmaxf(uv.x, -15.9f), 15.9f);
    float cy = fminf(fmaxf(uv.y, -15.9f), 15.9f);
    unsigned int tx = (unsigned int)__float2int_rn(fmaf(cx, 524288.0f, 8388608.0f));
    unsigned int ty = (unsigned int)__float2int_rn(fmaf(cy, 524288.0f, 8388608.0f));
    return ((unsigned long long)ty << 32) | tx;
}

// ======================= R19 fused cooperative kernel =======================
__global__ __launch_bounds__(512) void k_fused(
        const int* __restrict__ row, const int* __restrict__ col,
        const float* __restrict__ x,  const float* __restrict__ W1,
        const float* __restrict__ b1, const float* __restrict__ W2,
        const float* __restrict__ b2,
        int* __restrict__ P1, int* __restrict__ CNT,
        float* __restrict__ dis, float* __restrict__ t,
        float* __restrict__ degf, float2* __restrict__ u,
        float* __restrict__ Pp, float2* __restrict__ out,
        int n, int e, int NC, int PAD, int Cs, int Cv) {
    cg::grid_group grid = cg::this_grid();
    __shared__ __align__(16) unsigned long long binU[CW];   // 16 KB shared pool
    __shared__ int cur[MAXNC];
    int*   binI = (int*)binU;
    float* binF = (float*)binU;
    const int tid = threadIdx.x, wave = tid >> 6, lane = tid & 63;

    // ---- phase S: scatter into padded block-local regions ----
    {
        const int b = blockIdx.x;
        for (int j = tid; j < NC; j += 512) cur[j] = 0;
        __syncthreads();
        const int chunk = chunk_of(e);
        const int lo = b * chunk, end = min(lo + chunk, e);
        const size_t rbase = (size_t)b * NC * PAD;
        for (int i0 = lo + tid * 4; i0 + 3 < end; i0 += 2048) {
            int4 c4 = *reinterpret_cast<const int4*>(col + i0);
            int4 r4 = *reinterpret_cast<const int4*>(row + i0);
            int ca[4] = {c4.x, c4.y, c4.z, c4.w};
            int ra[4] = {r4.x, r4.y, r4.z, r4.w};
#pragma unroll
            for (int m = 0; m < 4; ++m) {
                int k = ca[m] >> CSH;
                int pos = atomicAdd(&cur[k], 1);
                if (pos < PAD)  // overflow guard (P ~1e-12 at PAD = mean+8sigma)
                    P1[rbase + (size_t)k * PAD + pos] =
                        (ra[m] << CSH) | (ca[m] & (CW - 1));
            }
        }
        const int tailStart = lo + ((end - lo) & ~3);
        for (int i = tailStart + tid; i < end; i += 512) {
            int c = col[i], r = row[i];
            int k = c >> CSH;
            int pos = atomicAdd(&cur[k], 1);
            if (pos < PAD)
                P1[rbase + (size_t)k * PAD + pos] = (r << CSH) | (c & (CW - 1));
        }
        __syncthreads();
        for (int j = tid; j < NC; j += 512) CNT[b * NC + j] = min(cur[j], PAD);
    }
    grid.sync();

    // ---- phase D: degree partials (LDS int bins) ----
    {
        int* Pd = (int*)Pp;
        for (int job = blockIdx.x; job < NC * Cs; job += NB1) {
            const int k = job / Cs, j = job % Cs;
            for (int q = tid; q < CW; q += 512) binI[q] = 0;
            __syncthreads();
            const int b0 = (j * NB1) / Cs, b1e = ((j + 1) * NB1) / Cs;
            for (int b = b0 + wave; b < b1e; b += 8) {
                const int cnt = CNT[b * NC + k];
                const int* seg = P1 + ((size_t)b * NC + k) * PAD;
                const int nv = cnt & ~3;
                for (int i = lane * 4; i < nv; i += 256) {
                    int4 a = *reinterpret_cast<const int4*>(seg + i);
                    atomicAdd(&binI[a.x & (CW - 1)], 1);
                    atomicAdd(&binI[a.y & (CW - 1)], 1);
                    atomicAdd(&binI[a.z & (CW - 1)], 1);
                    atomicAdd(&binI[a.w & (CW - 1)], 1);
                }
                for (int i = nv + lane; i < cnt; i += 64)
                    atomicAdd(&binI[seg[i] & (CW - 1)], 1);
            }
            __syncthreads();
            // dump index set == init index set per thread -> no extra barrier
            for (int q = tid; q < CW; q += 512)
                Pd[((size_t)k * Cs + j) * CW + q] = binI[q];
        }
    }
    grid.sync();

    // ---- phase P: prep (deg -> dis, t) ----
    {
        const int* Pd = (const int*)Pp;
        for (int c = blockIdx.x * 512 + tid; c < n; c += NB1 * 512) {
            int k = c >> CSH, l = c & (CW - 1);
            int d = 0;
            for (int j = 0; j < Cs; ++j) d += Pd[((size_t)k * Cs + j) * CW + l];
            degf[c] = (float)d;
            float di = rsqrtf(1.0f + (float)d);
            dis[c] = di;
            t[c] = di * x[c];
        }
    }
    grid.sync();

    // ---- phase A1: layer-1 aggregate (LDS float bins) ----
    {
        for (int job = blockIdx.x; job < NC * Cs; job += NB1) {
            const int k = job / Cs, j = job % Cs;
            for (int q = tid; q < CW; q += 512) binF[q] = 0.0f;
            __syncthreads();
            const int b0 = (j * NB1) / Cs, b1e = ((j + 1) * NB1) / Cs;
            for (int b = b0 + wave; b < b1e; b += 8) {
                const int cnt = CNT[b * NC + k];
                const int* seg = P1 + ((size_t)b * NC + k) * PAD;
                const int nv = cnt & ~3;
                for (int i = lane * 4; i < nv; i += 256) {
                    int4 a = *reinterpret_cast<const int4*>(seg + i);
                    float v0 = t[a.x >> CSH], v1 = t[a.y >> CSH];
                    float v2 = t[a.z >> CSH], v3 = t[a.w >> CSH];
                    atomicAdd(&binF[a.x & (CW - 1)], v0);
                    atomicAdd(&binF[a.y & (CW - 1)], v1);
                    atomicAdd(&binF[a.z & (CW - 1)], v2);
                    atomicAdd(&binF[a.w & (CW - 1)], v3);
                }
                for (int i = nv + lane; i < cnt; i += 64) {
                    int p = seg[i];
                    atomicAdd(&binF[p & (CW - 1)], t[p >> CSH]);
                }
            }
            __syncthreads();
            for (int q = tid; q < CW; q += 512)
                Pp[((size_t)k * Cs + j) * CW + q] = binF[q];
        }
    }
    grid.sync();

    // ---- phase M: per-node MLP ----
    {
        for (int c = blockIdx.x * 512 + tid; c < n; c += NB1 * 512) {
            int k = c >> CSH, l = c & (CW - 1);
            float S = 0.0f;
            for (int j = 0; j < Cs; ++j) S += Pp[((size_t)k * Cs + j) * CW + l];
            float di = dis[c];
            float s = di * (S + t[c]);
            float a0 = 0.0f, a1 = 0.0f;
#pragma unroll
            for (int j = 0; j < 16; ++j) {
                float hh = fmaxf(fmaf(s, W1[j], b1[j]), 0.0f);
                a0 = fmaf(W2[j],      hh, a0);
                a1 = fmaf(W2[16 + j], hh, a1);
            }
            u[c] = make_float2(di * a0, di * a1);
        }
    }
    grid.sync();

    // ---- phase A2: layer-2 aggregate (one u64 atomic, biased fixed-point) ----
    {
        unsigned long long* Pq = (unsigned long long*)Pp;
        for (int job = blockIdx.x; job < NC * Cv; job += NB1) {
            const int k = job / Cv, j = job % Cv;
            for (int q = tid; q < CW; q += 512) binU[q] = 0ull;
            __syncthreads();
            const int b0 = (j * NB1) / Cv, b1e = ((j + 1) * NB1) / Cv;
            for (int b = b0 + wave; b < b1e; b += 8) {
                const int cnt = CNT[b * NC + k];
                const int* seg = P1 + ((size_t)b * NC + k) * PAD;
                const int nv = cnt & ~3;
                for (int i = lane * 4; i < nv; i += 256) {
                    int4 a = *reinterpret_cast<const int4*>(seg + i);
                    unsigned long long q0 = pack_u(u[a.x >> CSH]);
                    unsigned long long q1 = pack_u(u[a.y >> CSH]);
                    unsigned long long q2 = pack_u(u[a.z >> CSH]);
                    unsigned long long q3 = pack_u(u[a.w >> CSH]);
                    atomicAdd(&binU[a.x & (CW - 1)], q0);
                    atomicAdd(&binU[a.y & (CW - 1)], q1);
                    atomicAdd(&binU[a.z & (CW - 1)], q2);
                    atomicAdd(&binU[a.w & (CW - 1)], q3);
                }
                for (int i = nv + lane; i < cnt; i += 64) {
                    int p = seg[i];
                    atomicAdd(&binU[p & (CW - 1)], pack_u(u[p >> CSH]));
                }
            }
            __syncthreads();
            for (int q = tid; q < CW; q += 512)
                Pq[((size_t)k * Cv + j) * CW + q] = binU[q];
        }
    }
    grid.sync();

    // ---- phase O: unpack + combine + write ----
    {
        const unsigned long long* Pq = (const unsigned long long*)Pp;
        for (int c = blockIdx.x * 512 + tid; c < n; c += NB1 * 512) {
            int k = c >> CSH, l = c & (CW - 1);
            unsigned long long S = 0ull;
            for (int j = 0; j < Cv; ++j) S += Pq[((size_t)k * Cv + j) * CW + l];
            double dg = (double)degf[c] * 8388608.0;
            double sx = ((double)(unsigned int)(S & 0xffffffffULL) - dg) * (1.0 / 524288.0);
            double sy = ((double)(unsigned int)(S >> 32)            - dg) * (1.0 / 524288.0);
            float di = dis[c];
            float2 uc = u[c];
            out[c] = make_float2(b2[0] + di * ((float)sx + uc.x),
                                 b2[1] + di * ((float)sy + uc.y));
        }
    }
}

// ================= R13 kernels (fallback path, proven 228us) =================
__global__ __launch_bounds__(256) void k_scatter(const int* __restrict__ row,
        const int* __restrict__ col, int* __restrict__ P1, int* __restrict__ CNT,
        int e, int NC, int PAD) {
    __shared__ int cur[MAXNC];
    const int b = blockIdx.x, tid = threadIdx.x;
    for (int j = tid; j < NC; j += 256) cur[j] = 0;
    __syncthreads();
    const int chunk = chunk_of(e);
    const int lo = b * chunk, end = min(lo + chunk, e);
    const size_t rbase = (size_t)b * NC * PAD;
    for (int i0 = lo + tid * 4; i0 + 3 < end; i0 += 1024) {
        int4 c4 = *reinterpret_cast<const int4*>(col + i0);
        int4 r4 = *reinterpret_cast<const int4*>(row + i0);
        int ca[4] = {c4.x, c4.y, c4.z, c4.w};
        int ra[4] = {r4.x, r4.y, r4.z, r4.w};
#pragma unroll
        for (int m = 0; m < 4; ++m) {
            int k = ca[m] >> CSH;
            int pos = atomicAdd(&cur[k], 1);
            if (pos < PAD)
                P1[rbase + (size_t)k * PAD + pos] = (ra[m] << CSH) | (ca[m] & (CW - 1));
        }
    }
    const int tailStart = lo + ((end - lo) & ~3);
    for (int i = tailStart + tid; i < end; i += 256) {
        int c = col[i], r = row[i];
        int k = c >> CSH;
        int pos = atomicAdd(&cur[k], 1);
        if (pos < PAD)
            P1[rbase + (size_t)k * PAD + pos] = (r << CSH) | (c & (CW - 1));
    }
    __syncthreads();
    for (int j = tid; j < NC; j += 256) CNT[b * NC + j] = min(cur[j], PAD);
}

__global__ __launch_bounds__(512) void k_deg(const int* __restrict__ P1,
        const int* __restrict__ CNT, int* __restrict__ Pd, int NC, int C, int PAD) {
    __shared__ __align__(16) int bin[CW];
    const int k = blockIdx.x / C, j = blockIdx.x % C;
    const int tid = threadIdx.x, wave = tid >> 6, lane = tid & 63;
    for (int q = tid; q < CW; q += 512) bin[q] = 0;
    __syncthreads();
    const int b0 = (j * NB1) / C, b1 = ((j + 1) * NB1) / C;
    for (int b = b0 + wave; b < b1; b += 8) {
        const int cnt = CNT[b * NC + k];
        const int* seg = P1 + ((size_t)b * NC + k) * PAD;
        const int nv = cnt & ~3;
        for (int i = lane * 4; i < nv; i += 256) {
            int4 a = *reinterpret_cast<const int4*>(seg + i);
            atomicAdd(&bin[a.x & (CW - 1)], 1); atomicAdd(&bin[a.y & (CW - 1)], 1);
            atomicAdd(&bin[a.z & (CW - 1)], 1); atomicAdd(&bin[a.w & (CW - 1)], 1);
        }
        for (int i = nv + lane; i < cnt; i += 64)
            atomicAdd(&bin[seg[i] & (CW - 1)], 1);
    }
    __syncthreads();
    int4* o4 = reinterpret_cast<int4*>(Pd + ((size_t)k * C + j) * CW);
    const int4* b4 = reinterpret_cast<const int4*>(bin);
    for (int q = tid; q < CW / 4; q += 512) o4[q] = b4[q];
}

__global__ __launch_bounds__(512) void k_aggf(const int* __restrict__ P1,
        const int* __restrict__ CNT, const float* __restrict__ src,
        float* __restrict__ Pf, int NC, int C, int PAD) {
    __shared__ __align__(16) float bin[CW];
    const int k = blockIdx.x / C, j = blockIdx.x % C;
    const int tid = threadIdx.x, wave = tid >> 6, lane = tid & 63;
    for (int q = tid; q < CW; q += 512) bin[q] = 0.0f;
    __syncthreads();
    const int b0 = (j * NB1) / C, b1 = ((j + 1) * NB1) / C;
    for (int b = b0 + wave; b < b1; b += 8) {
        const int cnt = CNT[b * NC + k];
        const int* seg = P1 + ((size_t)b * NC + k) * PAD;
        const int nv = cnt & ~3;
        for (int i = lane * 4; i < nv; i += 256) {
            int4 a = *reinterpret_cast<const int4*>(seg + i);
            float v0 = src[a.x >> CSH], v1 = src[a.y >> CSH];
            float v2 = src[a.z >> CSH], v3 = src[a.w >> CSH];
            atomicAdd(&bin[a.x & (CW - 1)], v0); atomicAdd(&bin[a.y & (CW - 1)], v1);
            atomicAdd(&bin[a.z & (CW - 1)], v2); atomicAdd(&bin[a.w & (CW - 1)], v3);
        }
        for (int i = nv + lane; i < cnt; i += 64) {
            int p = seg[i];
            atomicAdd(&bin[p & (CW - 1)], src[p >> CSH]);
        }
    }
    __syncthreads();
    float4* o4 = reinterpret_cast<float4*>(Pf + ((size_t)k * C + j) * CW);
    const float4* b4 = reinterpret_cast<const float4*>(bin);
    for (int q = tid; q < CW / 4; q += 512) o4[q] = b4[q];
}

__global__ __launch_bounds__(512) void k_agg2f(const int* __restrict__ P1,
        const int* __restrict__ CNT, const float2* __restrict__ u,
        unsigned long long* __restrict__ Pq, int NC, int C, int PAD) {
    __shared__ unsigned long long bin[CW];   // 16 KB
    const int k = blockIdx.x / C, j = blockIdx.x % C;
    const int tid = threadIdx.x, wave = tid >> 6, lane = tid & 63;
    for (int q = tid; q < CW; q += 512) bin[q] = 0ull;
    __syncthreads();
    const int b0 = (j * NB1) / C, b1 = ((j + 1) * NB1) / C;
    for (int b = b0 + wave; b < b1; b += 8) {
        const int cnt = CNT[b * NC + k];
        const int* seg = P1 + ((size_t)b * NC + k) * PAD;
        const int nv = cnt & ~3;
        for (int i = lane * 4; i < nv; i += 256) {
            int4 a = *reinterpret_cast<const int4*>(seg + i);
            unsigned long long q0 = pack_u(u[a.x >> CSH]);
            unsigned long long q1 = pack_u(u[a.y >> CSH]);
            unsigned long long q2 = pack_u(u[a.z >> CSH]);
            unsigned long long q3 = pack_u(u[a.w >> CSH]);
            atomicAdd(&bin[a.x & (CW - 1)], q0); atomicAdd(&bin[a.y & (CW - 1)], q1);
            atomicAdd(&bin[a.z & (CW - 1)], q2); atomicAdd(&bin[a.w & (CW - 1)], q3);
        }
        for (int i = nv + lane; i < cnt; i += 64) {
            int p = seg[i];
            atomicAdd(&bin[p & (CW - 1)], pack_u(u[p >> CSH]));
        }
    }
    __syncthreads();
    unsigned long long* o = Pq + ((size_t)k * C + j) * CW;
    for (int q = tid; q < CW; q += 512) o[q] = bin[q];
}

__global__ void k_prep(const int* __restrict__ Pd, const float* __restrict__ x,
        float* __restrict__ dis, float* __restrict__ t, float* __restrict__ degf,
        int n, int C) {
    int c = blockIdx.x * blockDim.x + threadIdx.x;
    if (c >= n) return;
    int k = c >> CSH, l = c & (CW - 1);
    int d = 0;
    for (int j = 0; j < C; ++j) d += Pd[((size_t)k * C + j) * CW + l];
    degf[c] = (float)d;
    float di = rsqrtf(1.0f + (float)d);
    dis[c] = di;
    t[c] = di * x[c];
}

__global__ void k_mlp(const float* __restrict__ Pf, const float* __restrict__ dis,
        const float* __restrict__ t, const float* __restrict__ W1,
        const float* __restrict__ b1, const float* __restrict__ W2,
        float2* __restrict__ u, int n, int C) {
    int c = blockIdx.x * blockDim.x + threadIdx.x;
    if (c >= n) return;
    int k = c >> CSH, l = c & (CW - 1);
    float S = 0.0f;
    for (int j = 0; j < C; ++j) S += Pf[((size_t)k * C + j) * CW + l];
    float di = dis[c];
    float s = di * (S + t[c]);
    float a0 = 0.0f, a1 = 0.0f;
#pragma unroll
    for (int j = 0; j < 16; ++j) {
        float hh = fmaxf(fmaf(s, W1[j], b1[j]), 0.0f);
        a0 = fmaf(W2[j],      hh, a0);
        a1 = fmaf(W2[16 + j], hh, a1);
    }
    u[c] = make_float2(di * a0, di * a1);
}

__global__ void k_out(const unsigned long long* __restrict__ Pq,
        const float* __restrict__ dis, const float* __restrict__ degf,
        const float2* __restrict__ u, const float* __restrict__ b2,
        float2* __restrict__ out, int n, int C) {
    int c = blockIdx.x * blockDim.x + threadIdx.x;
    if (c >= n) return;
    int k = c >> CSH, l = c & (CW - 1);
    unsigned long long S = 0ull;
    for (int j = 0; j < C; ++j) S += Pq[((size_t)k * C + j) * CW + l];
    double dg = (double)degf[c] * 8388608.0;
    double sx = ((double)(unsigned int)(S & 0xffffffffULL) - dg) * (1.0 / 524288.0);
    double sy = ((double)(unsigned int)(S >> 32)            - dg) * (1.0 / 524288.0);
    float di = dis[c];
    float2 uc = u[c];
    out[c] = make_float2(b2[0] + di * ((float)sx + uc.x),
                         b2[1] + di * ((float)sy + uc.y));
}

// ---------- generic atomic fallback (any n/e, slow but correct) ----------
__global__ void f_init_deg(float* deg, int n) {
    int i = blockIdx.x * blockDim.x + threadIdx.x;
    if (i < n) deg[i] = 1.0f;
}
__global__ void f_deg(const int* col, float* deg, int e) {
    int i = blockIdx.x * blockDim.x + threadIdx.x;
    if (i < e) atomicAdd(&deg[col[i]], 1.0f);
}
__global__ void f_dis_self(const float* x, float* deg_dis, float* s, int n) {
    int i = blockIdx.x * blockDim.x + threadIdx.x;
    if (i < n) { float di = rsqrtf(deg_dis[i]); deg_dis[i] = di; s[i] = di * di * x[i]; }
}
__global__ void f_agg1(const int* row, const int* col, const float* dis,
                       const float* x, float* s, int e) {
    int i = blockIdx.x * blockDim.x + threadIdx.x;
    if (i < e) { int r = row[i], c = col[i]; atomicAdd(&s[c], dis[r] * dis[c] * x[r]); }
}
__global__ void f_mlp(const float* s, const float* dis, const float* W1,
                      const float* b1, const float* W2, const float* b2,
                      float* h2, float* out, int n) {
    int i = blockIdx.x * blockDim.x + threadIdx.x;
    if (i < n) {
        float sv = s[i], a0 = 0.0f, a1 = 0.0f;
#pragma unroll
        for (int j = 0; j < 16; ++j) {
            float h1 = fmaxf(sv * W1[j] + b1[j], 0.0f);
            a0 = fmaf(W2[j], h1, a0); a1 = fmaf(W2[16 + j], h1, a1);
        }
        h2[2 * i] = a0; h2[2 * i + 1] = a1;
        float d2 = dis[i] * dis[i];
        out[2 * i] = b2[0] + d2 * a0; out[2 * i + 1] = b2[1] + d2 * a1;
    }
}
__global__ void f_agg2(const int* row, const int* col, const float* dis,
                       const float* h2, float* out, int e) {
    int i = blockIdx.x * blockDim.x + threadIdx.x;
    if (i < e) {
        int r = row[i], c = col[i];
        float nm = dis[r] * dis[c];
        float2 hv = *reinterpret_cast<const float2*>(&h2[2 * r]);
        atomicAdd(&out[2 * c], nm * hv.x);
        atomicAdd(&out[2 * c + 1], nm * hv.y);
    }
}
// -------------------------------------------------------------------------

extern "C" void kernel_launch(void* const* d_in, const int* in_sizes, int n_in,
                              void* d_out, int out_size, void* d_ws, size_t ws_size,
                              hipStream_t stream) {
    const float* x  = (const float*)d_in[0];
    const int*   ei = (const int*)d_in[1];
    const float* W1 = (const float*)d_in[2];
    const float* b1 = (const float*)d_in[3];
    const float* W2 = (const float*)d_in[4];
    const float* b2 = (const float*)d_in[5];

    const int n = in_sizes[0];
    const int e = in_sizes[1] / 2;
    const int* row = ei;
    const int* col = ei + e;

    const int NC = (n + CW - 1) >> CSH;
    const size_t NCW = (size_t)NC * CW;

    // PAD = mean + 8*sigma + 32 (binomial tail; overflow P ~1e-12/cell)
    const int chunk = chunk_of(e);
    const int lam = NC > 0 ? chunk / NC : 0;
    int PAD = lam + 8 * (int)std::sqrt((double)(lam > 0 ? lam : 1)) + 32;
    PAD = (PAD + 3) & ~3;

    // ws (4B units): P1[NB1*NC*PAD] | CNT[NB1*NC] | dis[n] | t[n] | degf[n] | u[2n] | Pp
    const size_t ws4 = ws_size / 4;
    const size_t p1sz = (size_t)NB1 * NC * PAD;
    size_t base4 = p1sz + (size_t)NB1 * NC + 5ull * (size_t)n;
    base4 = (base4 + 3) & ~(size_t)3;
    long long avail = (long long)ws4 - (long long)base4;
    int Cs = (avail > 0) ? (int)min((long long)32, avail / (long long)NCW) : 0;
    int Cv = (avail > 0) ? (int)min((long long)24, avail / (long long)(2 * NCW)) : 0;

    const int gn = (n + 255) / 256;
    // Guards: u64 packing needs indeg<256 (e<=100n); NC>=4 avoids cursor
    // same-address meltdown; ws must fit padded regions + partials.
    if (NC > MAXNC || NC < 4 || Cs < 2 || Cv < 2 ||
        (long long)e > 100ll * (long long)n) {
        float* dis = (float*)d_ws; float* s = dis + n; float* h2 = s + n;
        const int ge = (e + 255) / 256;
        f_init_deg<<<gn, 256, 0, stream>>>(dis, n);
        f_deg<<<ge, 256, 0, stream>>>(col, dis, e);
        f_dis_self<<<gn, 256, 0, stream>>>(x, dis, s, n);
        f_agg1<<<ge, 256, 0, stream>>>(row, col, dis, x, s, e);
        f_mlp<<<gn, 256, 0, stream>>>(s, dis, W1, b1, W2, b2, h2, (float*)d_out, n);
        f_agg2<<<ge, 256, 0, stream>>>(row, col, dis, h2, (float*)d_out, e);
        return;
    }

    int*    P1   = (int*)d_ws;
    int*    CNT  = P1 + p1sz;
    float*  dis  = (float*)(CNT + (size_t)NB1 * NC);
    float*  t    = dis + n;
    float*  degf = t + n;
    float2* u    = (float2*)(degf + n);
    float*  Pp   = (float*)((char*)d_ws + base4 * 4);   // partials (int/float/u64)
    float2* outp = (float2*)d_out;

    // ---- R19: one cooperative launch (runtime-gated, falls back to R13) ----
    static int coop_ok = -1;
    if (coop_ok < 0) {
        int dev = 0, attr = 0, mab = 0;
        hipGetDevice(&dev);
        hipDeviceGetAttribute(&attr, hipDeviceAttributeCooperativeLaunch, dev);
        hipOccupancyMaxActiveBlocksPerMultiprocessor(&mab, k_fused, 512, 0);
        coop_ok = (attr != 0 && mab >= 2) ? 1 : 0;   // need 2 blocks/CU for 512
    }
    if (coop_ok == 1) {
        int en = e, nn = n, ncc = NC, pad = PAD, cs = Cs, cv = Cv;
        void* args[] = { (void*)&row, (void*)&col, (void*)&x, (void*)&W1,
                         (void*)&b1, (void*)&W2, (void*)&b2, (void*)&P1,
                         (void*)&CNT, (void*)&dis, (void*)&t, (void*)&degf,
                         (void*)&u, (void*)&Pp, (void*)&outp,
                         (void*)&nn, (void*)&en, (void*)&ncc, (void*)&pad,
                         (void*)&cs, (void*)&cv };
        hipError_t rc = hipLaunchCooperativeKernel(k_fused, dim3(NB1), dim3(512),
                                                   args, 0, stream);
        if (rc == hipSuccess) return;
        // launch rejected -> fall through to R13
    }

    // ---- R13 multi-launch path (proven 228us) ----
    k_scatter<<<NB1, 256, 0, stream>>>(row, col, P1, CNT, e, NC, PAD);
    k_deg    <<<NC * Cs, 512, 0, stream>>>(P1, CNT, (int*)Pp, NC, Cs, PAD);
    k_prep   <<<gn, 256, 0, stream>>>((const int*)Pp, x, dis, t, degf, n, Cs);
    k_aggf   <<<NC * Cs, 512, 0, stream>>>(P1, CNT, t, Pp, NC, Cs, PAD);
    k_mlp    <<<gn, 256, 0, stream>>>(Pp, dis, t, W1, b1, W2, u, n, Cs);
    k_agg2f  <<<NC * Cv, 512, 0, stream>>>(P1, CNT, u, (unsigned long long*)Pp, NC, Cv, PAD);
    k_out    <<<gn, 256, 0, stream>>>((const unsigned long long*)Pp, dis, degf, u, b2,
                                      (float2*)d_out, n, Cv);
}

// Round 7
// 226.943 us; speedup vs baseline: 2.8085x; 2.8085x over previous
//
#include <hip/hip_runtime.h>
#include <cmath>

// GCN 2-layer, dims 1 -> 16 -> 2, N=100K, E=6.4M.
//
// Model (R1..R19, counter-validated):
//  - 4 edge passes (scatter, deg, aggf, agg2u64) + 3 node kernels + ~46us
//    launch gaps. Passes are LATENCY-bound (267cyc/wave-atomic vs ~12cyc DS
//    throughput), cured by MORE WAVES, not per-thread ILP:
//    R18 proved it: scatter 256->512thr saved ~17us (inferred), while
//    pair-cell ILP in the bin passes REGRESSED aggf +7us (mask overhead).
//  - Bin passes already run 512thr x 4 blocks/CU = 32 waves/CU (max).
//  - Dead ends (counter-proven): atomic-free gathers (R14/15, write-amp +
//    dependent-load latency), global atomics (R16, 29G/s write-through),
//    cooperative fusion (R17/R19, ~550us both with/without VGPR squeeze ->
//    fixed residency + barrier tails + device-scope fences).
// R20: R13 bodies exactly for deg/aggf/agg2f (pair-cell reverted); scatter
// at 1024 thr/block (32 waves/CU, HW max) with 8-wide unroll.

static constexpr int CSH   = 11;           // log2 bucket width
static constexpr int CW    = 1 << CSH;     // 2048 nodes / bucket
static constexpr int MAXNC = 64;           // n <= 131072
static constexpr int NB1   = 512;          // scatter blocks / segments

__host__ __device__ __forceinline__ int chunk_of(int e) {
    return ((e + NB1 * 4 - 1) / (NB1 * 4)) * 4;   // 4-aligned per-block chunk
}

// ---- 1) scatter into padded block-local regions, local cursors ----
// 1024 thr: 2 blocks/CU -> 2048 thr/CU = 32 waves/CU (vs 8 @256thr in R13).
__global__ __launch_bounds__(1024) void k_scatter(const int* __restrict__ row,
        const int* __restrict__ col, int* __restrict__ P1, int* __restrict__ CNT,
        int e, int NC, int PAD) {
    __shared__ int cur[MAXNC];
    const int b = blockIdx.x, tid = threadIdx.x;
    for (int j = tid; j < NC; j += 1024) cur[j] = 0;
    __syncthreads();
    const int chunk = chunk_of(e);
    const int lo = b * chunk, end = min(lo + chunk, e);
    const size_t rbase = (size_t)b * NC * PAD;
    for (int i0 = lo + tid * 8; i0 + 7 < end; i0 += 8192) {
        int4 c4a = *reinterpret_cast<const int4*>(col + i0);
        int4 c4b = *reinterpret_cast<const int4*>(col + i0 + 4);
        int4 r4a = *reinterpret_cast<const int4*>(row + i0);
        int4 r4b = *reinterpret_cast<const int4*>(row + i0 + 4);
        int ca[8] = {c4a.x, c4a.y, c4a.z, c4a.w, c4b.x, c4b.y, c4b.z, c4b.w};
        int ra[8] = {r4a.x, r4a.y, r4a.z, r4a.w, r4b.x, r4b.y, r4b.z, r4b.w};
#pragma unroll
        for (int m = 0; m < 8; ++m) {
            int k = ca[m] >> CSH;
            int pos = atomicAdd(&cur[k], 1);
            if (pos < PAD)   // overflow guard (P ~1e-12 at PAD = mean+8sigma)
                P1[rbase + (size_t)k * PAD + pos] = (ra[m] << CSH) | (ca[m] & (CW - 1));
        }
    }
    const int tailStart = lo + ((end - lo) & ~7);
    for (int i = tailStart + tid; i < end; i += 1024) {
        int c = col[i], r = row[i];
        int k = c >> CSH;
        int pos = atomicAdd(&cur[k], 1);
        if (pos < PAD)
            P1[rbase + (size_t)k * PAD + pos] = (r << CSH) | (c & (CW - 1));
    }
    __syncthreads();
    for (int j = tid; j < NC; j += 1024) CNT[b * NC + j] = min(cur[j], PAD);
}

// ---- 2) degree pass: per-segment int4 loop, LDS int bins (R13 body) ----
__global__ __launch_bounds__(512) void k_deg(const int* __restrict__ P1,
        const int* __restrict__ CNT, int* __restrict__ Pd, int NC, int C, int PAD) {
    __shared__ __align__(16) int bin[CW];
    const int k = blockIdx.x / C, j = blockIdx.x % C;
    const int tid = threadIdx.x, wave = tid >> 6, lane = tid & 63;
    for (int q = tid; q < CW; q += 512) bin[q] = 0;
    __syncthreads();
    const int b0 = (j * NB1) / C, b1 = ((j + 1) * NB1) / C;
    for (int b = b0 + wave; b < b1; b += 8) {
        const int cnt = CNT[b * NC + k];
        const int* seg = P1 + ((size_t)b * NC + k) * PAD;
        const int nv = cnt & ~3;
        for (int i = lane * 4; i < nv; i += 256) {
            int4 a = *reinterpret_cast<const int4*>(seg + i);
            atomicAdd(&bin[a.x & (CW - 1)], 1); atomicAdd(&bin[a.y & (CW - 1)], 1);
            atomicAdd(&bin[a.z & (CW - 1)], 1); atomicAdd(&bin[a.w & (CW - 1)], 1);
        }
        for (int i = nv + lane; i < cnt; i += 64)
            atomicAdd(&bin[seg[i] & (CW - 1)], 1);
    }
    __syncthreads();
    int4* o4 = reinterpret_cast<int4*>(Pd + ((size_t)k * C + j) * CW);
    const int4* b4 = reinterpret_cast<const int4*>(bin);
    for (int q = tid; q < CW / 4; q += 512) o4[q] = b4[q];
}

// ---- 3) layer-1 aggregate: bin[col] += src[row] (R13 body) ----
__global__ __launch_bounds__(512) void k_aggf(const int* __restrict__ P1,
        const int* __restrict__ CNT, const float* __restrict__ src,
        float* __restrict__ Pf, int NC, int C, int PAD) {
    __shared__ __align__(16) float bin[CW];
    const int k = blockIdx.x / C, j = blockIdx.x % C;
    const int tid = threadIdx.x, wave = tid >> 6, lane = tid & 63;
    for (int q = tid; q < CW; q += 512) bin[q] = 0.0f;
    __syncthreads();
    const int b0 = (j * NB1) / C, b1 = ((j + 1) * NB1) / C;
    for (int b = b0 + wave; b < b1; b += 8) {
        const int cnt = CNT[b * NC + k];
        const int* seg = P1 + ((size_t)b * NC + k) * PAD;
        const int nv = cnt & ~3;
        for (int i = lane * 4; i < nv; i += 256) {
            int4 a = *reinterpret_cast<const int4*>(seg + i);
            float v0 = src[a.x >> CSH], v1 = src[a.y >> CSH];
            float v2 = src[a.z >> CSH], v3 = src[a.w >> CSH];
            atomicAdd(&bin[a.x & (CW - 1)], v0); atomicAdd(&bin[a.y & (CW - 1)], v1);
            atomicAdd(&bin[a.z & (CW - 1)], v2); atomicAdd(&bin[a.w & (CW - 1)], v3);
        }
        for (int i = nv + lane; i < cnt; i += 64) {
            int p = seg[i];
            atomicAdd(&bin[p & (CW - 1)], src[p >> CSH]);
        }
    }
    __syncthreads();
    float4* o4 = reinterpret_cast<float4*>(Pf + ((size_t)k * C + j) * CW);
    const float4* b4 = reinterpret_cast<const float4*>(bin);
    for (int q = tid; q < CW / 4; q += 512) o4[q] = b4[q];
}

// ---- 4) layer-2 aggregate: ONE u64 atomic, biased fixed-point (R13 body) ----
__device__ __forceinline__ unsigned long long pack_u(float2 uv) {
    float cx = fminf(fmaxf(uv.x, -15.9f), 15.9f);
    float cy = fminf(fmaxf(uv.y, -15.9f), 15.9f);
    unsigned int tx = (unsigned int)__float2int_rn(fmaf(cx, 524288.0f, 8388608.0f));
    unsigned int ty = (unsigned int)__float2int_rn(fmaf(cy, 524288.0f, 8388608.0f));
    return ((unsigned long long)ty << 32) | tx;
}

__global__ __launch_bounds__(512) void k_agg2f(const int* __restrict__ P1,
        const int* __restrict__ CNT, const float2* __restrict__ u,
        unsigned long long* __restrict__ Pq, int NC, int C, int PAD) {
    __shared__ unsigned long long bin[CW];   // 16 KB
    const int k = blockIdx.x / C, j = blockIdx.x % C;
    const int tid = threadIdx.x, wave = tid >> 6, lane = tid & 63;
    for (int q = tid; q < CW; q += 512) bin[q] = 0ull;
    __syncthreads();
    const int b0 = (j * NB1) / C, b1 = ((j + 1) * NB1) / C;
    for (int b = b0 + wave; b < b1; b += 8) {
        const int cnt = CNT[b * NC + k];
        const int* seg = P1 + ((size_t)b * NC + k) * PAD;
        const int nv = cnt & ~3;
        for (int i = lane * 4; i < nv; i += 256) {
            int4 a = *reinterpret_cast<const int4*>(seg + i);
            unsigned long long q0 = pack_u(u[a.x >> CSH]);
            unsigned long long q1 = pack_u(u[a.y >> CSH]);
            unsigned long long q2 = pack_u(u[a.z >> CSH]);
            unsigned long long q3 = pack_u(u[a.w >> CSH]);
            atomicAdd(&bin[a.x & (CW - 1)], q0); atomicAdd(&bin[a.y & (CW - 1)], q1);
            atomicAdd(&bin[a.z & (CW - 1)], q2); atomicAdd(&bin[a.w & (CW - 1)], q3);
        }
        for (int i = nv + lane; i < cnt; i += 64) {
            int p = seg[i];
            atomicAdd(&bin[p & (CW - 1)], pack_u(u[p >> CSH]));
        }
    }
    __syncthreads();
    unsigned long long* o = Pq + ((size_t)k * C + j) * CW;
    for (int q = tid; q < CW; q += 512) o[q] = bin[q];
}

// ---- 5) node kernels ----
__global__ void k_prep(const int* __restrict__ Pd, const float* __restrict__ x,
        float* __restrict__ dis, float* __restrict__ t, float* __restrict__ degf,
        int n, int C) {
    int c = blockIdx.x * blockDim.x + threadIdx.x;
    if (c >= n) return;
    int k = c >> CSH, l = c & (CW - 1);
    int d = 0;
    for (int j = 0; j < C; ++j) d += Pd[((size_t)k * C + j) * CW + l];
    degf[c] = (float)d;
    float di = rsqrtf(1.0f + (float)d);
    dis[c] = di;
    t[c] = di * x[c];
}

__global__ void k_mlp(const float* __restrict__ Pf, const float* __restrict__ dis,
        const float* __restrict__ t, const float* __restrict__ W1,
        const float* __restrict__ b1, const float* __restrict__ W2,
        float2* __restrict__ u, int n, int C) {
    int c = blockIdx.x * blockDim.x + threadIdx.x;
    if (c >= n) return;
    int k = c >> CSH, l = c & (CW - 1);
    float S = 0.0f;
    for (int j = 0; j < C; ++j) S += Pf[((size_t)k * C + j) * CW + l];
    float di = dis[c];
    float s = di * (S + t[c]);
    float a0 = 0.0f, a1 = 0.0f;
#pragma unroll
    for (int j = 0; j < 16; ++j) {
        float hh = fmaxf(fmaf(s, W1[j], b1[j]), 0.0f);
        a0 = fmaf(W2[j],      hh, a0);
        a1 = fmaf(W2[16 + j], hh, a1);
    }
    u[c] = make_float2(di * a0, di * a1);
}

__global__ void k_out(const unsigned long long* __restrict__ Pq,
        const float* __restrict__ dis, const float* __restrict__ degf,
        const float2* __restrict__ u, const float* __restrict__ b2,
        float2* __restrict__ out, int n, int C) {
    int c = blockIdx.x * blockDim.x + threadIdx.x;
    if (c >= n) return;
    int k = c >> CSH, l = c & (CW - 1);
    unsigned long long S = 0ull;
    for (int j = 0; j < C; ++j) S += Pq[((size_t)k * C + j) * CW + l];
    double dg = (double)degf[c] * 8388608.0;
    double sx = ((double)(unsigned int)(S & 0xffffffffULL) - dg) * (1.0 / 524288.0);
    double sy = ((double)(unsigned int)(S >> 32)            - dg) * (1.0 / 524288.0);
    float di = dis[c];
    float2 uc = u[c];
    out[c] = make_float2(b2[0] + di * ((float)sx + uc.x),
                         b2[1] + di * ((float)sy + uc.y));
}

// ---------- generic atomic fallback (any n/e, slow but correct) ----------
__global__ void f_init_deg(float* deg, int n) {
    int i = blockIdx.x * blockDim.x + threadIdx.x;
    if (i < n) deg[i] = 1.0f;
}
__global__ void f_deg(const int* col, float* deg, int e) {
    int i = blockIdx.x * blockDim.x + threadIdx.x;
    if (i < e) atomicAdd(&deg[col[i]], 1.0f);
}
__global__ void f_dis_self(const float* x, float* deg_dis, float* s, int n) {
    int i = blockIdx.x * blockDim.x + threadIdx.x;
    if (i < n) { float di = rsqrtf(deg_dis[i]); deg_dis[i] = di; s[i] = di * di * x[i]; }
}
__global__ void f_agg1(const int* row, const int* col, const float* dis,
                       const float* x, float* s, int e) {
    int i = blockIdx.x * blockDim.x + threadIdx.x;
    if (i < e) { int r = row[i], c = col[i]; atomicAdd(&s[c], dis[r] * dis[c] * x[r]); }
}
__global__ void f_mlp(const float* s, const float* dis, const float* W1,
                      const float* b1, const float* W2, const float* b2,
                      float* h2, float* out, int n) {
    int i = blockIdx.x * blockDim.x + threadIdx.x;
    if (i < n) {
        float sv = s[i], a0 = 0.0f, a1 = 0.0f;
#pragma unroll
        for (int j = 0; j < 16; ++j) {
            float h1 = fmaxf(sv * W1[j] + b1[j], 0.0f);
            a0 = fmaf(W2[j], h1, a0); a1 = fmaf(W2[16 + j], h1, a1);
        }
        h2[2 * i] = a0; h2[2 * i + 1] = a1;
        float d2 = dis[i] * dis[i];
        out[2 * i] = b2[0] + d2 * a0; out[2 * i + 1] = b2[1] + d2 * a1;
    }
}
__global__ void f_agg2(const int* row, const int* col, const float* dis,
                       const float* h2, float* out, int e) {
    int i = blockIdx.x * blockDim.x + threadIdx.x;
    if (i < e) {
        int r = row[i], c = col[i];
        float nm = dis[r] * dis[c];
        float2 hv = *reinterpret_cast<const float2*>(&h2[2 * r]);
        atomicAdd(&out[2 * c], nm * hv.x);
        atomicAdd(&out[2 * c + 1], nm * hv.y);
    }
}
// -------------------------------------------------------------------------

extern "C" void kernel_launch(void* const* d_in, const int* in_sizes, int n_in,
                              void* d_out, int out_size, void* d_ws, size_t ws_size,
                              hipStream_t stream) {
    const float* x  = (const float*)d_in[0];
    const int*   ei = (const int*)d_in[1];
    const float* W1 = (const float*)d_in[2];
    const float* b1 = (const float*)d_in[3];
    const float* W2 = (const float*)d_in[4];
    const float* b2 = (const float*)d_in[5];

    const int n = in_sizes[0];
    const int e = in_sizes[1] / 2;
    const int* row = ei;
    const int* col = ei + e;

    const int NC = (n + CW - 1) >> CSH;
    const size_t NCW = (size_t)NC * CW;

    // PAD = mean + 8*sigma + 32 (binomial tail; overflow P ~1e-12/cell)
    const int chunk = chunk_of(e);
    const int lam = NC > 0 ? chunk / NC : 0;
    int PAD = lam + 8 * (int)std::sqrt((double)(lam > 0 ? lam : 1)) + 32;
    PAD = (PAD + 3) & ~3;

    // ws (4B units): P1[NB1*NC*PAD] | CNT[NB1*NC] | dis[n] | t[n] | degf[n] | u[2n] | Pp
    const size_t ws4 = ws_size / 4;
    const size_t p1sz = (size_t)NB1 * NC * PAD;
    size_t base4 = p1sz + (size_t)NB1 * NC + 5ull * (size_t)n;
    base4 = (base4 + 3) & ~(size_t)3;
    long long avail = (long long)ws4 - (long long)base4;
    int Cs = (avail > 0) ? (int)min((long long)32, avail / (long long)NCW) : 0;
    int Cv = (avail > 0) ? (int)min((long long)24, avail / (long long)(2 * NCW)) : 0;

    // Guards: u64 packing needs indeg<256 (e<=100n); NC>=4 avoids cursor
    // same-address meltdown; ws must fit padded regions + partials.
    const int gn = (n + 255) / 256;
    if (NC > MAXNC || NC < 4 || Cs < 2 || Cv < 2 ||
        (long long)e > 100ll * (long long)n) {
        float* dis = (float*)d_ws; float* s = dis + n; float* h2 = s + n;
        const int ge = (e + 255) / 256;
        f_init_deg<<<gn, 256, 0, stream>>>(dis, n);
        f_deg<<<ge, 256, 0, stream>>>(col, dis, e);
        f_dis_self<<<gn, 256, 0, stream>>>(x, dis, s, n);
        f_agg1<<<ge, 256, 0, stream>>>(row, col, dis, x, s, e);
        f_mlp<<<gn, 256, 0, stream>>>(s, dis, W1, b1, W2, b2, h2, (float*)d_out, n);
        f_agg2<<<ge, 256, 0, stream>>>(row, col, dis, h2, (float*)d_out, e);
        return;
    }

    int*    P1   = (int*)d_ws;
    int*    CNT  = P1 + p1sz;
    float*  dis  = (float*)(CNT + (size_t)NB1 * NC);
    float*  t    = dis + n;
    float*  degf = t + n;
    float2* u    = (float2*)(degf + n);
    float*  Pp   = (float*)((char*)d_ws + base4 * 4);   // partials (int/float/u64)

    k_scatter<<<NB1, 1024, 0, stream>>>(row, col, P1, CNT, e, NC, PAD);
    k_deg    <<<NC * Cs, 512, 0, stream>>>(P1, CNT, (int*)Pp, NC, Cs, PAD);
    k_prep   <<<gn, 256, 0, stream>>>((const int*)Pp, x, dis, t, degf, n, Cs);
    k_aggf   <<<NC * Cs, 512, 0, stream>>>(P1, CNT, t, Pp, NC, Cs, PAD);
    k_mlp    <<<gn, 256, 0, stream>>>(Pp, dis, t, W1, b1, W2, u, n, Cs);
    k_agg2f  <<<NC * Cv, 512, 0, stream>>>(P1, CNT, u, (unsigned long long*)Pp, NC, Cv, PAD);
    k_out    <<<gn, 256, 0, stream>>>((const unsigned long long*)Pp, dis, degf, u, b2,
                                      (float2*)d_out, n, Cv);
}